// Round 8
// baseline (106.126 us; speedup 1.0000x reference)
//
#include <hip/hip_runtime.h>
#include <math.h>

// DRMM pipeline for MI355X (gfx950) — round 8: lane-pair token split for 2x
// wave concurrency.
// Phase 1: 2048 blocks x 256 thr (8 blocks/CU -> 32 waves/CU). Lanes 2k/2k+1
//   own the two 256B halves of one token row (same-instruction loads -> no
//   cross-wave L1 decoupling like R6). Pair-combine via shfl_xor(.,1); even
//   lane bins q0-3, odd lane bins q4-7. Query bases scalarized; per-lane
//   half*64 element offset rides the voffset.
// Phase 2: MLP 30->128->64->32->1 + gate softmax + output. 512 blocks x 512 thr.
// B=32, D=16, L=512, Q=8, E=128, NB=30

#define BN_INV 0.99950037468777346f  // np.float32(1/sqrt(1+1e-3))

__device__ __forceinline__ float shflx(float v, int m) {
    return __shfl_xor(v, m, 64);
}

__device__ __forceinline__ int sel8i(int v0, int v1, int v2, int v3,
                                     int v4, int v5, int v6, int v7, int i) {
    int a0 = (i & 1) ? v1 : v0;
    int a1 = (i & 1) ? v3 : v2;
    int a2 = (i & 1) ? v5 : v4;
    int a3 = (i & 1) ? v7 : v6;
    int b0 = (i & 2) ? a1 : a0;
    int b1 = (i & 2) ? a3 : a2;
    return (i & 4) ? b1 : b0;
}

// fast tanh: clamp(+-9) then (e^2x-1)/(e^2x+1) via hw exp2 + rcp.
// tanh(9)==1.0f in fp32 so the clamp is exact; rel err ~2e-7. (R6/R7: absmax 0.0)
__device__ __forceinline__ float tanh_fast(float x) {
    float y = fminf(fmaxf(x, -9.0f), 9.0f);
    float t = exp2f(y * 2.8853901817f);      // e^(2y)
    return (t - 1.0f) * __builtin_amdgcn_rcpf(t + 1.0f);
}

__device__ __forceinline__ float4 ld4(const float* base, int elem_off) {
    return *(const float4*)(base + elem_off);
}

// ---------------- Phase 1: gather + histogram (lane-pair per token) ---------
template <bool PARTIAL>
__global__ __launch_bounds__(256, 8)
void drmm_hist(const int* __restrict__ doc,
               const int* __restrict__ query,
               const float* __restrict__ emb,
               float* __restrict__ hist_out)
{
    __shared__ float histw[4][8][32];   // [wave][q][bin(+2 pad)]
    __shared__ float qn_s[8];

    const int tid  = threadIdx.x;
    const int bid  = blockIdx.x;        // 0..2047, 128 tokens each
    const int b    = bid >> 6;          // 64 blocks per batch (8192 tokens)
    const int wid  = tid >> 6;
    const int lane = tid & 63;
    const int half = tid & 1;           // element half of the pair

    for (int i = tid; i < 4 * 8 * 32; i += 256) ((float*)histw)[i] = 0.0f;

    // wave-uniform query row indices (scalarized)
    const int* qrow = query + b * 8;
    const int qi0 = __builtin_amdgcn_readfirstlane(qrow[0]);
    const int qi1 = __builtin_amdgcn_readfirstlane(qrow[1]);
    const int qi2 = __builtin_amdgcn_readfirstlane(qrow[2]);
    const int qi3 = __builtin_amdgcn_readfirstlane(qrow[3]);
    const int qi4 = __builtin_amdgcn_readfirstlane(qrow[4]);
    const int qi5 = __builtin_amdgcn_readfirstlane(qrow[5]);
    const int qi6 = __builtin_amdgcn_readfirstlane(qrow[6]);
    const int qi7 = __builtin_amdgcn_readfirstlane(qrow[7]);

    const float* qb0 = emb + (size_t)qi0 * 128;   // scalar bases
    const float* qb1 = emb + (size_t)qi1 * 128;
    const float* qb2 = emb + (size_t)qi2 * 128;
    const float* qb3 = emb + (size_t)qi3 * 128;
    const float* qb4 = emb + (size_t)qi4 * 128;
    const float* qb5 = emb + (size_t)qi5 * 128;
    const float* qb6 = emb + (size_t)qi6 * 128;
    const float* qb7 = emb + (size_t)qi7 * 128;

    // query norms: wave 0 (same op order as rounds 5-7; absmax was 0.0)
    if (wid == 0) {
        int q = lane >> 3, j = lane & 7;
        int qis = sel8i(qi0, qi1, qi2, qi3, qi4, qi5, qi6, qi7, q);
        const float4* qq = (const float4*)(emb + (size_t)qis * 128) + j * 4;
        float s = 0.f;
#pragma unroll
        for (int c = 0; c < 4; ++c) {
            float4 x = qq[c];
            s = fmaf(x.x, x.x, s); s = fmaf(x.y, x.y, s);
            s = fmaf(x.z, x.z, s); s = fmaf(x.w, x.w, s);
        }
        s += shflx(s, 1); s += shflx(s, 2); s += shflx(s, 4);
        if (j == 0) qn_s[q] = sqrtf(s);
    }
    __syncthreads();

    // ---- lane-pair half-row streaming: 16 x float4 = 256 B per lane ----
    const int gtok = bid * 128 + (tid >> 1);       // 0..262143
    const int idx  = doc[gtok];                    // pair reads same addr
    const int hoff = half * 64;                    // element offset
    const float* rbase = emb + (size_t)idx * 128;

    float dd = 0.f;
    float dq0 = 0.f, dq1 = 0.f, dq2 = 0.f, dq3 = 0.f;
    float dq4 = 0.f, dq5 = 0.f, dq6 = 0.f, dq7 = 0.f;

    float4 vb[8];
#pragma unroll
    for (int p = 0; p < 8; ++p) vb[p] = ld4(rbase, hoff + p * 4);

#pragma unroll
    for (int c = 0; c < 2; ++c) {
        float4 nb[8];
        if (c < 1) {
#pragma unroll
            for (int p = 0; p < 8; ++p) nb[p] = ld4(rbase, hoff + (8 + p) * 4);
        }
#pragma unroll
        for (int p = 0; p < 8; ++p) {
            const int eo = hoff + (c * 8 + p) * 4;
            float4 v  = vb[p];
            float4 a0 = ld4(qb0, eo), a1 = ld4(qb1, eo);
            float4 a2 = ld4(qb2, eo), a3 = ld4(qb3, eo);
            float4 a4 = ld4(qb4, eo), a5 = ld4(qb5, eo);
            float4 a6 = ld4(qb6, eo), a7 = ld4(qb7, eo);
            dd  = fmaf(v.x, v.x, dd);  dd  = fmaf(v.y, v.y, dd);
            dd  = fmaf(v.z, v.z, dd);  dd  = fmaf(v.w, v.w, dd);
#define ACC(A, Dq) Dq = fmaf(v.x, A.x, Dq); Dq = fmaf(v.y, A.y, Dq); \
                   Dq = fmaf(v.z, A.z, Dq); Dq = fmaf(v.w, A.w, Dq);
            ACC(a0, dq0) ACC(a1, dq1) ACC(a2, dq2) ACC(a3, dq3)
            ACC(a4, dq4) ACC(a5, dq5) ACC(a6, dq6) ACC(a7, dq7)
#undef ACC
        }
        if (c < 1) {
#pragma unroll
            for (int p = 0; p < 8; ++p) vb[p] = nb[p];
        }
    }

    // pair-combine: each lane gets the full 128-dim sums (9 shuffles)
    dd  += shflx(dd, 1);
    dq0 += shflx(dq0, 1); dq1 += shflx(dq1, 1);
    dq2 += shflx(dq2, 1); dq3 += shflx(dq3, 1);
    dq4 += shflx(dq4, 1); dq5 += shflx(dq5, 1);
    dq6 += shflx(dq6, 1); dq7 += shflx(dq7, 1);

    const float dn = sqrtf(dd);
#define DOBIN(J, DQ) {                                                  \
        float sim = DQ / (dn * qn_s[J] + 1e-8f);                        \
        float u = (sim - 0.001f) / 0.999f * 30.0f;                      \
        int bin = (int)floorf(u);                                       \
        bin = bin < 0 ? 0 : (bin > 29 ? 29 : bin);                      \
        atomicAdd(&histw[wid][J][bin], 1.0f);                           \
    }
    if (half == 0) {
        DOBIN(0, dq0) DOBIN(1, dq1) DOBIN(2, dq2) DOBIN(3, dq3)
    } else {
        DOBIN(4, dq4) DOBIN(5, dq5) DOBIN(6, dq6) DOBIN(7, dq7)
    }
#undef DOBIN
    __syncthreads();

    // flush 8q x 30 bins (exact integer counts)
    if (tid < 240) {
        int q = tid / 30, k = tid - q * 30;
        float s = histw[0][q][k] + histw[1][q][k]
                + histw[2][q][k] + histw[3][q][k];
        if (PARTIAL) {
            hist_out[(size_t)bid * 240 + tid] = s;
        } else {
            atomicAdd(&hist_out[(bid >> 2) * 240 + tid], s);
        }
    }
}

// ---------------- Phase 2: gate softmax + MLP + output ----------------
template <bool PARTIAL>
__global__ __launch_bounds__(512, 4)
void drmm_mlp(const float* __restrict__ hist_g,
              const int* __restrict__ query,
              const float* __restrict__ idf,
              const float* __restrict__ w_gate,
              const float* __restrict__ g_in, const float* __restrict__ b_in,
              const float* __restrict__ W0, const float* __restrict__ b0,
              const float* __restrict__ g0, const float* __restrict__ be0,
              const float* __restrict__ W1, const float* __restrict__ b1,
              const float* __restrict__ g1, const float* __restrict__ be1,
              const float* __restrict__ W2, const float* __restrict__ b2,
              const float* __restrict__ g2, const float* __restrict__ be2,
              const float* __restrict__ W3, const float* __restrict__ b3,
              const float* __restrict__ g3, const float* __restrict__ be3,
              float* __restrict__ out)
{
    __shared__ float xrow[8][30];
    __shared__ float h1s[8][128];
    __shared__ float h2s[8][64];
    __shared__ float h3s[8][32];
    __shared__ float gate_s[8];
    __shared__ float part[8];

    const int tid  = threadIdx.x;
    const int bd   = blockIdx.x;
    const int b    = bd >> 4;
    const int wid  = tid >> 6;
    const int lane = tid & 63;

    // Gate softmax: 8 parallel lanes (same op order as rounds 2-7).
    if (tid >= 504) {
        int q = tid - 504;
        float z = w_gate[q] * idf[query[b * 8 + q]];
        float m = z;
        m = fmaxf(m, shflx(m, 1)); m = fmaxf(m, shflx(m, 2)); m = fmaxf(m, shflx(m, 4));
        float e = expf(z - m);
        float s = e;
        s += shflx(s, 1); s += shflx(s, 2); s += shflx(s, 4);
        gate_s[q] = e / s;
    }

    if (tid < 240) {
        int q = tid / 30, k = tid - q * 30;
        float s;
        if (PARTIAL) {
            const float* hp = hist_g + (size_t)bd * 960 + tid;
            s = (hp[0] + hp[240]) + (hp[480] + hp[720]);  // exact int counts
        } else {
            s = hist_g[bd * 240 + tid];
        }
        xrow[q][k] = g_in[k] * (s * BN_INV) + b_in[k];
    }
    __syncthreads();

    // layer 1: 30 -> 128 (lane j computes outputs j and j+64); wave wid = q
    {
        float a0 = 0.f, a1 = 0.f;
#pragma unroll
        for (int k = 0; k < 30; ++k) {
            float xk = xrow[wid][k];
            a0 += xk * W0[k * 128 + lane];
            a1 += xk * W0[k * 128 + 64 + lane];
        }
        a0 += b0[lane]; a1 += b0[lane + 64];
        h1s[wid][lane]      = tanh_fast(g0[lane]      * (a0 * BN_INV) + be0[lane]);
        h1s[wid][lane + 64] = tanh_fast(g0[lane + 64] * (a1 * BN_INV) + be0[lane + 64]);
    }
    __syncthreads();

    // layer 2: 128 -> 64
    {
        float a = 0.f;
#pragma unroll 8
        for (int k = 0; k < 128; ++k) a += h1s[wid][k] * W1[k * 64 + lane];
        a += b1[lane];
        h2s[wid][lane] = tanh_fast(g1[lane] * (a * BN_INV) + be1[lane]);
    }
    __syncthreads();

    // layer 3: 64 -> 32
    if (lane < 32) {
        float a = 0.f;
#pragma unroll 8
        for (int k = 0; k < 64; ++k) a += h2s[wid][k] * W2[k * 32 + lane];
        a += b2[lane];
        h3s[wid][lane] = tanh_fast(g2[lane] * (a * BN_INV) + be2[lane]);
    }
    __syncthreads();

    // layer 4: 32 -> 1, gate weighting
    if (lane == 0) {
        float a = 0.f;
#pragma unroll
        for (int k = 0; k < 32; ++k) a += h3s[wid][k] * W3[k];
        a += b3[0];
        float y = tanh_fast(g3[0] * (a * BN_INV) + be3[0]);
        part[wid] = gate_s[wid] * y;
    }
    __syncthreads();

    if (tid == 0) {
        float s = 0.f;
#pragma unroll
        for (int q = 0; q < 8; ++q) s += part[q];
        out[bd] = s;
    }
}

extern "C" void kernel_launch(void* const* d_in, const int* in_sizes, int n_in,
                              void* d_out, int out_size, void* d_ws, size_t ws_size,
                              hipStream_t stream) {
    (void)in_sizes; (void)n_in; (void)out_size;
    const int*   doc    = (const int*)d_in[0];
    const int*   query  = (const int*)d_in[1];
    const float* emb    = (const float*)d_in[2];
    const float* idf    = (const float*)d_in[3];
    const float* w_gate = (const float*)d_in[4];
    const float* g_in   = (const float*)d_in[5];
    const float* b_in   = (const float*)d_in[6];
    const float* W0  = (const float*)d_in[7];
    const float* b0  = (const float*)d_in[8];
    const float* g0  = (const float*)d_in[9];
    const float* be0 = (const float*)d_in[10];
    const float* W1  = (const float*)d_in[11];
    const float* b1  = (const float*)d_in[12];
    const float* g1  = (const float*)d_in[13];
    const float* be1 = (const float*)d_in[14];
    const float* W2  = (const float*)d_in[15];
    const float* b2  = (const float*)d_in[16];
    const float* g2  = (const float*)d_in[17];
    const float* be2 = (const float*)d_in[18];
    const float* W3  = (const float*)d_in[19];
    const float* b3  = (const float*)d_in[20];
    const float* g3  = (const float*)d_in[21];
    const float* be3 = (const float*)d_in[22];

    float* hist_g = (float*)d_ws;
    const size_t need_partial = (size_t)2048 * 240 * sizeof(float); // 1.97 MB

    if (ws_size >= need_partial) {
        drmm_hist<true><<<dim3(2048), dim3(256), 0, stream>>>(doc, query, emb, hist_g);
        drmm_mlp<true><<<dim3(512), dim3(512), 0, stream>>>(
            hist_g, query, idf, w_gate, g_in, b_in,
            W0, b0, g0, be0, W1, b1, g1, be1,
            W2, b2, g2, be2, W3, b3, g3, be3, (float*)d_out);
    } else {
        hipMemsetAsync(hist_g, 0, 512 * 240 * sizeof(float), stream);
        drmm_hist<false><<<dim3(2048), dim3(256), 0, stream>>>(doc, query, emb, hist_g);
        drmm_mlp<false><<<dim3(512), dim3(512), 0, stream>>>(
            hist_g, query, idf, w_gate, g_in, b_in,
            W0, b0, g0, be0, W1, b1, g1, be1,
            W2, b2, g2, be2, W3, b3, g3, be3, (float*)d_out);
    }
}

// Round 9
// 57.678 us; speedup vs baseline: 1.8400x; 1.8400x over previous
//
#include <hip/hip_runtime.h>
#include <math.h>

// DRMM pipeline for MI355X (gfx950) — round 9: 8-lane cooperative rows with
// FULL-LINE loads (occupancy-proof FETCH) + 32 waves/CU.
// Phase 1: 8192 blocks x 256 thr. Group of 8 lanes owns one token; load k
//   covers row bytes [k*128, k*128+128) in ONE instruction (8 lanes x 16B)
//   -> every 128B line consumed at issue, no L1 temporal reuse needed.
//   Lane j accumulates dd+dq[8] over its 16 elems; 3-round wave butterfly
//   reduces all 8 groups at once; lane j bins query j.
// Phase 2: MLP 30->128->64->32->1 + gate softmax + output. 512 blocks x 512 thr.
// B=32, D=16, L=512, Q=8, E=128, NB=30

#define BN_INV 0.99950037468777346f  // np.float32(1/sqrt(1+1e-3))

__device__ __forceinline__ float shflx(float v, int m) {
    return __shfl_xor(v, m, 64);
}

__device__ __forceinline__ int sel8i(int v0, int v1, int v2, int v3,
                                     int v4, int v5, int v6, int v7, int i) {
    int a0 = (i & 1) ? v1 : v0;
    int a1 = (i & 1) ? v3 : v2;
    int a2 = (i & 1) ? v5 : v4;
    int a3 = (i & 1) ? v7 : v6;
    int b0 = (i & 2) ? a1 : a0;
    int b1 = (i & 2) ? a3 : a2;
    return (i & 4) ? b1 : b0;
}

__device__ __forceinline__ float sel8f(float v0, float v1, float v2, float v3,
                                       float v4, float v5, float v6, float v7, int i) {
    float a0 = (i & 1) ? v1 : v0;
    float a1 = (i & 1) ? v3 : v2;
    float a2 = (i & 1) ? v5 : v4;
    float a3 = (i & 1) ? v7 : v6;
    float b0 = (i & 2) ? a1 : a0;
    float b1 = (i & 2) ? a3 : a2;
    return (i & 4) ? b1 : b0;
}

// fast tanh: clamp(+-9) then (e^2x-1)/(e^2x+1) via hw exp2 + rcp.
// tanh(9)==1.0f in fp32 so the clamp is exact; rel err ~2e-7. (R6-R8: absmax 0.0)
__device__ __forceinline__ float tanh_fast(float x) {
    float y = fminf(fmaxf(x, -9.0f), 9.0f);
    float t = exp2f(y * 2.8853901817f);      // e^(2y)
    return (t - 1.0f) * __builtin_amdgcn_rcpf(t + 1.0f);
}

__device__ __forceinline__ float4 ld4(const float* base, int elem_off) {
    return *(const float4*)(base + elem_off);
}

// ---------------- Phase 1: gather + histogram (8-lane cooperative) ----------
template <bool PARTIAL>
__global__ __launch_bounds__(256, 8)
void drmm_hist(const int* __restrict__ doc,
               const int* __restrict__ query,
               const float* __restrict__ emb,
               float* __restrict__ hist_out)
{
    __shared__ float histw[4][8][32];   // [wave][q][bin(+2 pad)]
    __shared__ float qn_s[8];

    const int tid  = threadIdx.x;
    const int bid  = blockIdx.x;        // 0..8191: (bd, chunk-of-32-tokens)
    const int b    = bid >> 8;          // batch
    const int wid  = tid >> 6;
    const int lane = tid & 63;
    const int g    = lane >> 3;         // group in wave (0..7)
    const int j    = lane & 7;          // lane in group

    for (int i = tid; i < 4 * 8 * 32; i += 256) ((float*)histw)[i] = 0.0f;

    // wave-uniform query row indices (scalarized)
    const int* qrow = query + b * 8;
    const int qi0 = __builtin_amdgcn_readfirstlane(qrow[0]);
    const int qi1 = __builtin_amdgcn_readfirstlane(qrow[1]);
    const int qi2 = __builtin_amdgcn_readfirstlane(qrow[2]);
    const int qi3 = __builtin_amdgcn_readfirstlane(qrow[3]);
    const int qi4 = __builtin_amdgcn_readfirstlane(qrow[4]);
    const int qi5 = __builtin_amdgcn_readfirstlane(qrow[5]);
    const int qi6 = __builtin_amdgcn_readfirstlane(qrow[6]);
    const int qi7 = __builtin_amdgcn_readfirstlane(qrow[7]);

    const float* qb0 = emb + (size_t)qi0 * 128;
    const float* qb1 = emb + (size_t)qi1 * 128;
    const float* qb2 = emb + (size_t)qi2 * 128;
    const float* qb3 = emb + (size_t)qi3 * 128;
    const float* qb4 = emb + (size_t)qi4 * 128;
    const float* qb5 = emb + (size_t)qi5 * 128;
    const float* qb6 = emb + (size_t)qi6 * 128;
    const float* qb7 = emb + (size_t)qi7 * 128;

    // query norms: wave 0 (same op order as rounds 5-8; absmax was 0.0)
    if (wid == 0) {
        int q = lane >> 3, jj = lane & 7;
        int qis = sel8i(qi0, qi1, qi2, qi3, qi4, qi5, qi6, qi7, q);
        const float4* qq = (const float4*)(emb + (size_t)qis * 128) + jj * 4;
        float s = 0.f;
#pragma unroll
        for (int c = 0; c < 4; ++c) {
            float4 x = qq[c];
            s = fmaf(x.x, x.x, s); s = fmaf(x.y, x.y, s);
            s = fmaf(x.z, x.z, s); s = fmaf(x.w, x.w, s);
        }
        s += shflx(s, 1); s += shflx(s, 2); s += shflx(s, 4);
        if (jj == 0) qn_s[q] = sqrtf(s);
    }
    __syncthreads();

    // ---- cooperative row processing: group owns one token ----
    const int gtok = bid * 32 + wid * 8 + g;       // 0..262143
    const int idx  = doc[gtok];                    // 8 lanes read same entry
    const float* rbase = emb + (size_t)idx * 128;
    const int eo = j * 4;                          // lane's element offset

    float dd = 0.f;
    float dq0 = 0.f, dq1 = 0.f, dq2 = 0.f, dq3 = 0.f;
    float dq4 = 0.f, dq5 = 0.f, dq6 = 0.f, dq7 = 0.f;

    // row chunk k: one wave instruction covers 8 full 128B lines (8 groups).
    float4 r0 = ld4(rbase, eo);
    float4 r1 = ld4(rbase, eo + 32);

#define KSTEP(RV, KO) {                                                     \
        const int e = eo + (KO);                                            \
        float4 v  = RV;                                                     \
        float4 a0 = ld4(qb0, e), a1 = ld4(qb1, e);                          \
        float4 a2 = ld4(qb2, e), a3 = ld4(qb3, e);                          \
        float4 a4 = ld4(qb4, e), a5 = ld4(qb5, e);                          \
        float4 a6 = ld4(qb6, e), a7 = ld4(qb7, e);                          \
        dd = fmaf(v.x, v.x, dd); dd = fmaf(v.y, v.y, dd);                   \
        dd = fmaf(v.z, v.z, dd); dd = fmaf(v.w, v.w, dd);                   \
        dq0 = fmaf(v.x, a0.x, dq0); dq0 = fmaf(v.y, a0.y, dq0);             \
        dq0 = fmaf(v.z, a0.z, dq0); dq0 = fmaf(v.w, a0.w, dq0);             \
        dq1 = fmaf(v.x, a1.x, dq1); dq1 = fmaf(v.y, a1.y, dq1);             \
        dq1 = fmaf(v.z, a1.z, dq1); dq1 = fmaf(v.w, a1.w, dq1);             \
        dq2 = fmaf(v.x, a2.x, dq2); dq2 = fmaf(v.y, a2.y, dq2);             \
        dq2 = fmaf(v.z, a2.z, dq2); dq2 = fmaf(v.w, a2.w, dq2);             \
        dq3 = fmaf(v.x, a3.x, dq3); dq3 = fmaf(v.y, a3.y, dq3);             \
        dq3 = fmaf(v.z, a3.z, dq3); dq3 = fmaf(v.w, a3.w, dq3);             \
        dq4 = fmaf(v.x, a4.x, dq4); dq4 = fmaf(v.y, a4.y, dq4);             \
        dq4 = fmaf(v.z, a4.z, dq4); dq4 = fmaf(v.w, a4.w, dq4);             \
        dq5 = fmaf(v.x, a5.x, dq5); dq5 = fmaf(v.y, a5.y, dq5);             \
        dq5 = fmaf(v.z, a5.z, dq5); dq5 = fmaf(v.w, a5.w, dq5);             \
        dq6 = fmaf(v.x, a6.x, dq6); dq6 = fmaf(v.y, a6.y, dq6);             \
        dq6 = fmaf(v.z, a6.z, dq6); dq6 = fmaf(v.w, a6.w, dq6);             \
        dq7 = fmaf(v.x, a7.x, dq7); dq7 = fmaf(v.y, a7.y, dq7);             \
        dq7 = fmaf(v.z, a7.z, dq7); dq7 = fmaf(v.w, a7.w, dq7);             \
    }

    float4 r2 = ld4(rbase, eo + 64);
    KSTEP(r0, 0)
    float4 r3 = ld4(rbase, eo + 96);
    KSTEP(r1, 32)
    KSTEP(r2, 64)
    KSTEP(r3, 96)
#undef KSTEP

    // 3-round butterfly within each 8-lane group (wave-wide, all groups at once)
#pragma unroll
    for (int off = 1; off <= 4; off <<= 1) {
        dd  += shflx(dd, off);
        dq0 += shflx(dq0, off); dq1 += shflx(dq1, off);
        dq2 += shflx(dq2, off); dq3 += shflx(dq3, off);
        dq4 += shflx(dq4, off); dq5 += shflx(dq5, off);
        dq6 += shflx(dq6, off); dq7 += shflx(dq7, off);
    }

    // lane j bins query j (all 64 lanes active)
    {
        float dqj = sel8f(dq0, dq1, dq2, dq3, dq4, dq5, dq6, dq7, j);
        float sim = dqj / (sqrtf(dd) * qn_s[j] + 1e-8f);
        float u = (sim - 0.001f) / 0.999f * 30.0f;   // ref op order
        int bin = (int)floorf(u);
        bin = bin < 0 ? 0 : (bin > 29 ? 29 : bin);
        atomicAdd(&histw[wid][j][bin], 1.0f);
    }
    __syncthreads();

    // flush 8q x 30 bins (exact integer counts)
    if (tid < 240) {
        int q = tid / 30, k = tid - q * 30;
        float s = histw[0][q][k] + histw[1][q][k]
                + histw[2][q][k] + histw[3][q][k];
        if (PARTIAL) {
            hist_out[(size_t)bid * 240 + tid] = s;
        } else {
            atomicAdd(&hist_out[(bid >> 4) * 240 + tid], s);
        }
    }
}

// ---------------- Phase 2: gate softmax + MLP + output ----------------
template <bool PARTIAL>
__global__ __launch_bounds__(512, 4)
void drmm_mlp(const float* __restrict__ hist_g,
              const int* __restrict__ query,
              const float* __restrict__ idf,
              const float* __restrict__ w_gate,
              const float* __restrict__ g_in, const float* __restrict__ b_in,
              const float* __restrict__ W0, const float* __restrict__ b0,
              const float* __restrict__ g0, const float* __restrict__ be0,
              const float* __restrict__ W1, const float* __restrict__ b1,
              const float* __restrict__ g1, const float* __restrict__ be1,
              const float* __restrict__ W2, const float* __restrict__ b2,
              const float* __restrict__ g2, const float* __restrict__ be2,
              const float* __restrict__ W3, const float* __restrict__ b3,
              const float* __restrict__ g3, const float* __restrict__ be3,
              float* __restrict__ out)
{
    __shared__ float xrow[8][30];
    __shared__ float h1s[8][128];
    __shared__ float h2s[8][64];
    __shared__ float h3s[8][32];
    __shared__ float gate_s[8];
    __shared__ float part[8];

    const int tid  = threadIdx.x;
    const int bd   = blockIdx.x;
    const int b    = bd >> 4;
    const int wid  = tid >> 6;
    const int lane = tid & 63;

    // Gate softmax: 8 parallel lanes (same op order as rounds 2-8).
    if (tid >= 504) {
        int q = tid - 504;
        float z = w_gate[q] * idf[query[b * 8 + q]];
        float m = z;
        m = fmaxf(m, shflx(m, 1)); m = fmaxf(m, shflx(m, 2)); m = fmaxf(m, shflx(m, 4));
        float e = expf(z - m);
        float s = e;
        s += shflx(s, 1); s += shflx(s, 2); s += shflx(s, 4);
        gate_s[q] = e / s;
    }

    if (tid < 240) {
        int q = tid / 30, k = tid - q * 30;
        float s;
        if (PARTIAL) {
            const float* hp = hist_g + (size_t)bd * 16 * 240 + tid;
            float s0 = 0.f;
#pragma unroll
            for (int p = 0; p < 16; ++p) s0 += hp[p * 240];  // exact int counts
            s = s0;
        } else {
            s = hist_g[bd * 240 + tid];
        }
        xrow[q][k] = g_in[k] * (s * BN_INV) + b_in[k];
    }
    __syncthreads();

    // layer 1: 30 -> 128 (lane j computes outputs j and j+64); wave wid = q
    {
        float a0 = 0.f, a1 = 0.f;
#pragma unroll
        for (int k = 0; k < 30; ++k) {
            float xk = xrow[wid][k];
            a0 += xk * W0[k * 128 + lane];
            a1 += xk * W0[k * 128 + 64 + lane];
        }
        a0 += b0[lane]; a1 += b0[lane + 64];
        h1s[wid][lane]      = tanh_fast(g0[lane]      * (a0 * BN_INV) + be0[lane]);
        h1s[wid][lane + 64] = tanh_fast(g0[lane + 64] * (a1 * BN_INV) + be0[lane + 64]);
    }
    __syncthreads();

    // layer 2: 128 -> 64
    {
        float a = 0.f;
#pragma unroll 8
        for (int k = 0; k < 128; ++k) a += h1s[wid][k] * W1[k * 64 + lane];
        a += b1[lane];
        h2s[wid][lane] = tanh_fast(g1[lane] * (a * BN_INV) + be1[lane]);
    }
    __syncthreads();

    // layer 3: 64 -> 32
    if (lane < 32) {
        float a = 0.f;
#pragma unroll 8
        for (int k = 0; k < 64; ++k) a += h2s[wid][k] * W2[k * 32 + lane];
        a += b2[lane];
        h3s[wid][lane] = tanh_fast(g2[lane] * (a * BN_INV) + be2[lane]);
    }
    __syncthreads();

    // layer 4: 32 -> 1, gate weighting
    if (lane == 0) {
        float a = 0.f;
#pragma unroll
        for (int k = 0; k < 32; ++k) a += h3s[wid][k] * W3[k];
        a += b3[0];
        float y = tanh_fast(g3[0] * (a * BN_INV) + be3[0]);
        part[wid] = gate_s[wid] * y;
    }
    __syncthreads();

    if (tid == 0) {
        float s = 0.f;
#pragma unroll
        for (int q = 0; q < 8; ++q) s += part[q];
        out[bd] = s;
    }
}

extern "C" void kernel_launch(void* const* d_in, const int* in_sizes, int n_in,
                              void* d_out, int out_size, void* d_ws, size_t ws_size,
                              hipStream_t stream) {
    (void)in_sizes; (void)n_in; (void)out_size;
    const int*   doc    = (const int*)d_in[0];
    const int*   query  = (const int*)d_in[1];
    const float* emb    = (const float*)d_in[2];
    const float* idf    = (const float*)d_in[3];
    const float* w_gate = (const float*)d_in[4];
    const float* g_in   = (const float*)d_in[5];
    const float* b_in   = (const float*)d_in[6];
    const float* W0  = (const float*)d_in[7];
    const float* b0  = (const float*)d_in[8];
    const float* g0  = (const float*)d_in[9];
    const float* be0 = (const float*)d_in[10];
    const float* W1  = (const float*)d_in[11];
    const float* b1  = (const float*)d_in[12];
    const float* g1  = (const float*)d_in[13];
    const float* be1 = (const float*)d_in[14];
    const float* W2  = (const float*)d_in[15];
    const float* b2  = (const float*)d_in[16];
    const float* g2  = (const float*)d_in[17];
    const float* be2 = (const float*)d_in[18];
    const float* W3  = (const float*)d_in[19];
    const float* b3  = (const float*)d_in[20];
    const float* g3  = (const float*)d_in[21];
    const float* be3 = (const float*)d_in[22];

    float* hist_g = (float*)d_ws;
    const size_t need_partial = (size_t)8192 * 240 * sizeof(float); // 7.86 MB

    if (ws_size >= need_partial) {
        drmm_hist<true><<<dim3(8192), dim3(256), 0, stream>>>(doc, query, emb, hist_g);
        drmm_mlp<true><<<dim3(512), dim3(512), 0, stream>>>(
            hist_g, query, idf, w_gate, g_in, b_in,
            W0, b0, g0, be0, W1, b1, g1, be1,
            W2, b2, g2, be2, W3, b3, g3, be3, (float*)d_out);
    } else {
        hipMemsetAsync(hist_g, 0, 512 * 240 * sizeof(float), stream);
        drmm_hist<false><<<dim3(8192), dim3(256), 0, stream>>>(doc, query, emb, hist_g);
        drmm_mlp<false><<<dim3(512), dim3(512), 0, stream>>>(
            hist_g, query, idf, w_gate, g_in, b_in,
            W0, b0, g0, be0, W1, b1, g1, be1,
            W2, b2, g2, be2, W3, b3, g3, be3, (float*)d_out);
    }
}

// Round 10
// 47.624 us; speedup vs baseline: 2.2284x; 1.2111x over previous
//
#include <hip/hip_runtime.h>
#include <math.h>

// DRMM pipeline for MI355X (gfx950) — round 10: R7 structure + FORCED 8-deep
// rolling double-buffer row bursts (asm liveness pins) + LDS-staged q vectors
// (q reads on lgkmcnt, independent of row-load vmcnt).
// Phase 1: 1024 blocks x 256 thr; lane = one doc token; row streamed as 4
//   bursts of 8 float4; bursts overlap via A/B register buffers.
// Phase 2: MLP 30->128->64->32->1 + gate softmax + output. 512 blocks x 512 thr.
// B=32, D=16, L=512, Q=8, E=128, NB=30

#define BN_INV 0.99950037468777346f  // np.float32(1/sqrt(1+1e-3))

__device__ __forceinline__ float shflx(float v, int m) {
    return __shfl_xor(v, m, 64);
}

__device__ __forceinline__ int sel8i(int v0, int v1, int v2, int v3,
                                     int v4, int v5, int v6, int v7, int i) {
    int a0 = (i & 1) ? v1 : v0;
    int a1 = (i & 1) ? v3 : v2;
    int a2 = (i & 1) ? v5 : v4;
    int a3 = (i & 1) ? v7 : v6;
    int b0 = (i & 2) ? a1 : a0;
    int b1 = (i & 2) ? a3 : a2;
    return (i & 4) ? b1 : b0;
}

// fast tanh: clamp(+-9) then (e^2x-1)/(e^2x+1) via hw exp2 + rcp. (R6-R9: absmax 0.0)
__device__ __forceinline__ float tanh_fast(float x) {
    float y = fminf(fmaxf(x, -9.0f), 9.0f);
    float t = exp2f(y * 2.8853901817f);      // e^(2y)
    return (t - 1.0f) * __builtin_amdgcn_rcpf(t + 1.0f);
}

// liveness pin: forces all 4 components materialized in VGPRs at this point
#define PIN4(V) asm volatile("" : "+v"((V).x), "+v"((V).y), "+v"((V).z), "+v"((V).w))

// ---------------- Phase 1: gather + histogram (forced-depth bursts) ---------
template <bool PARTIAL>
__global__ __launch_bounds__(256, 4)
void drmm_hist(const int* __restrict__ doc,
               const int* __restrict__ query,
               const float* __restrict__ emb,
               float* __restrict__ hist_out)
{
    __shared__ float histw[4][8][32];   // [wave][q][bin(+2 pad)]
    __shared__ float qn_s[8];
    __shared__ float4 qlds[8][32];      // 8 q rows x 32 float4 = 4KB

    const int tid  = threadIdx.x;
    const int bid  = blockIdx.x;        // (bd, token-half)
    const int bd   = bid >> 1;
    const int b    = bid >> 5;          // bd >> 4
    const int wid  = tid >> 6;
    const int lane = tid & 63;

    // prefetch doc index immediately (hide its latency under setup)
    const int gtok = bid * 256 + tid;          // 0..262143
    const int idx  = doc[gtok];

    for (int i = tid; i < 4 * 8 * 32; i += 256) ((float*)histw)[i] = 0.0f;

    // wave-uniform query row indices (scalarized)
    const int* qrow = query + b * 8;
    const int qi0 = __builtin_amdgcn_readfirstlane(qrow[0]);
    const int qi1 = __builtin_amdgcn_readfirstlane(qrow[1]);
    const int qi2 = __builtin_amdgcn_readfirstlane(qrow[2]);
    const int qi3 = __builtin_amdgcn_readfirstlane(qrow[3]);
    const int qi4 = __builtin_amdgcn_readfirstlane(qrow[4]);
    const int qi5 = __builtin_amdgcn_readfirstlane(qrow[5]);
    const int qi6 = __builtin_amdgcn_readfirstlane(qrow[6]);
    const int qi7 = __builtin_amdgcn_readfirstlane(qrow[7]);

    // stage the 8 q rows into LDS: 256 threads x 1 float4 each
    {
        int q = tid >> 5;        // 0..7
        int c = tid & 31;        // 0..31
        int qis = sel8i(qi0, qi1, qi2, qi3, qi4, qi5, qi6, qi7, q);
        qlds[q][c] = *((const float4*)(emb + (size_t)qis * 128) + c);
    }

    // query norms: wave 0 — UNCHANGED op order from R5-R9 (absmax 0.0)
    if (wid == 0) {
        int q = lane >> 3, jj = lane & 7;
        int qis = sel8i(qi0, qi1, qi2, qi3, qi4, qi5, qi6, qi7, q);
        const float4* qq = (const float4*)(emb + (size_t)qis * 128) + jj * 4;
        float s = 0.f;
#pragma unroll
        for (int c = 0; c < 4; ++c) {
            float4 x = qq[c];
            s = fmaf(x.x, x.x, s); s = fmaf(x.y, x.y, s);
            s = fmaf(x.z, x.z, s); s = fmaf(x.w, x.w, s);
        }
        s += shflx(s, 1); s += shflx(s, 2); s += shflx(s, 4);
        if (jj == 0) qn_s[q] = sqrtf(s);
    }
    __syncthreads();

    const float4* rp = (const float4*)(emb + (size_t)idx * 128);

    float dd = 0.f;
    float dq0 = 0.f, dq1 = 0.f, dq2 = 0.f, dq3 = 0.f;
    float dq4 = 0.f, dq5 = 0.f, dq6 = 0.f, dq7 = 0.f;

    // per-chunk compute: FMA sequence IDENTICAL to R7's KSTEP (bit-exact),
    // q values from LDS (lgkmcnt — independent of row vmcnt).
#define CSTEP(V, S) {                                                       \
        float4 v  = (V);                                                    \
        float4 a0 = qlds[0][S], a1 = qlds[1][S];                            \
        float4 a2 = qlds[2][S], a3 = qlds[3][S];                            \
        float4 a4 = qlds[4][S], a5 = qlds[5][S];                            \
        float4 a6 = qlds[6][S], a7 = qlds[7][S];                            \
        dd = fmaf(v.x, v.x, dd); dd = fmaf(v.y, v.y, dd);                   \
        dd = fmaf(v.z, v.z, dd); dd = fmaf(v.w, v.w, dd);                   \
        dq0 = fmaf(v.x, a0.x, dq0); dq0 = fmaf(v.y, a0.y, dq0);             \
        dq0 = fmaf(v.z, a0.z, dq0); dq0 = fmaf(v.w, a0.w, dq0);             \
        dq1 = fmaf(v.x, a1.x, dq1); dq1 = fmaf(v.y, a1.y, dq1);             \
        dq1 = fmaf(v.z, a1.z, dq1); dq1 = fmaf(v.w, a1.w, dq1);             \
        dq2 = fmaf(v.x, a2.x, dq2); dq2 = fmaf(v.y, a2.y, dq2);             \
        dq2 = fmaf(v.z, a2.z, dq2); dq2 = fmaf(v.w, a2.w, dq2);             \
        dq3 = fmaf(v.x, a3.x, dq3); dq3 = fmaf(v.y, a3.y, dq3);             \
        dq3 = fmaf(v.z, a3.z, dq3); dq3 = fmaf(v.w, a3.w, dq3);             \
        dq4 = fmaf(v.x, a4.x, dq4); dq4 = fmaf(v.y, a4.y, dq4);             \
        dq4 = fmaf(v.z, a4.z, dq4); dq4 = fmaf(v.w, a4.w, dq4);             \
        dq5 = fmaf(v.x, a5.x, dq5); dq5 = fmaf(v.y, a5.y, dq5);             \
        dq5 = fmaf(v.z, a5.z, dq5); dq5 = fmaf(v.w, a5.w, dq5);             \
        dq6 = fmaf(v.x, a6.x, dq6); dq6 = fmaf(v.y, a6.y, dq6);             \
        dq6 = fmaf(v.z, a6.z, dq6); dq6 = fmaf(v.w, a6.w, dq6);             \
        dq7 = fmaf(v.x, a7.x, dq7); dq7 = fmaf(v.y, a7.y, dq7);             \
        dq7 = fmaf(v.z, a7.z, dq7); dq7 = fmaf(v.w, a7.w, dq7);             \
    }

    float4 A[8], B[8];
    // burst 0 -> A (chunks 0-7, line 0), burst 1 -> B (chunks 8-15, line 1)
#pragma unroll
    for (int p = 0; p < 8; ++p) A[p] = rp[p];
#pragma unroll
    for (int p = 0; p < 8; ++p) B[p] = rp[8 + p];
#pragma unroll
    for (int p = 0; p < 8; ++p) PIN4(A[p]);     // forces 16 loads issued, waits A only
#pragma unroll
    for (int p = 0; p < 8; ++p) CSTEP(A[p], p)  // compute chunks 0-7
#pragma unroll
    for (int p = 0; p < 8; ++p) A[p] = rp[16 + p];  // burst 2 -> A (line 2)
#pragma unroll
    for (int p = 0; p < 8; ++p) PIN4(B[p]);     // waits B (burst-2 in flight)
#pragma unroll
    for (int p = 0; p < 8; ++p) CSTEP(B[p], 8 + p)
#pragma unroll
    for (int p = 0; p < 8; ++p) B[p] = rp[24 + p];  // burst 3 -> B (line 3)
#pragma unroll
    for (int p = 0; p < 8; ++p) PIN4(A[p]);     // waits burst 2 (burst-3 in flight)
#pragma unroll
    for (int p = 0; p < 8; ++p) CSTEP(A[p], 16 + p)
#pragma unroll
    for (int p = 0; p < 8; ++p) PIN4(B[p]);     // waits burst 3
#pragma unroll
    for (int p = 0; p < 8; ++p) CSTEP(B[p], 24 + p)
#undef CSTEP

    const float dn = sqrtf(dd);
#define DOBIN(J, DQ) {                                                  \
        float sim = DQ / (dn * qn_s[J] + 1e-8f);                        \
        float u = (sim - 0.001f) / 0.999f * 30.0f;                      \
        int bin = (int)floorf(u);                                       \
        bin = bin < 0 ? 0 : (bin > 29 ? 29 : bin);                      \
        atomicAdd(&histw[wid][J][bin], 1.0f);                           \
    }
    DOBIN(0, dq0) DOBIN(1, dq1) DOBIN(2, dq2) DOBIN(3, dq3)
    DOBIN(4, dq4) DOBIN(5, dq5) DOBIN(6, dq6) DOBIN(7, dq7)
#undef DOBIN
    __syncthreads();

    // flush 8q x 30 bins (exact integer counts)
    if (tid < 240) {
        int q = tid / 30, k = tid - q * 30;
        float s = histw[0][q][k] + histw[1][q][k]
                + histw[2][q][k] + histw[3][q][k];
        if (PARTIAL) {
            hist_out[(size_t)bid * 240 + tid] = s;
        } else {
            atomicAdd(&hist_out[bd * 240 + tid], s);
        }
    }
}

// ---------------- Phase 2: gate softmax + MLP + output ----------------
template <bool PARTIAL>
__global__ __launch_bounds__(512, 4)
void drmm_mlp(const float* __restrict__ hist_g,
              const int* __restrict__ query,
              const float* __restrict__ idf,
              const float* __restrict__ w_gate,
              const float* __restrict__ g_in, const float* __restrict__ b_in,
              const float* __restrict__ W0, const float* __restrict__ b0,
              const float* __restrict__ g0, const float* __restrict__ be0,
              const float* __restrict__ W1, const float* __restrict__ b1,
              const float* __restrict__ g1, const float* __restrict__ be1,
              const float* __restrict__ W2, const float* __restrict__ b2,
              const float* __restrict__ g2, const float* __restrict__ be2,
              const float* __restrict__ W3, const float* __restrict__ b3,
              const float* __restrict__ g3, const float* __restrict__ be3,
              float* __restrict__ out)
{
    __shared__ float xrow[8][30];
    __shared__ float h1s[8][128];
    __shared__ float h2s[8][64];
    __shared__ float h3s[8][32];
    __shared__ float gate_s[8];
    __shared__ float part[8];

    const int tid  = threadIdx.x;
    const int bd   = blockIdx.x;
    const int b    = bd >> 4;
    const int wid  = tid >> 6;
    const int lane = tid & 63;

    // Gate softmax: 8 parallel lanes (same op order as rounds 2-9).
    if (tid >= 504) {
        int q = tid - 504;
        float z = w_gate[q] * idf[query[b * 8 + q]];
        float m = z;
        m = fmaxf(m, shflx(m, 1)); m = fmaxf(m, shflx(m, 2)); m = fmaxf(m, shflx(m, 4));
        float e = expf(z - m);
        float s = e;
        s += shflx(s, 1); s += shflx(s, 2); s += shflx(s, 4);
        gate_s[q] = e / s;
    }

    if (tid < 240) {
        int q = tid / 30, k = tid - q * 30;
        float s;
        if (PARTIAL) {
            const float* hp = hist_g + (size_t)bd * 480 + tid;
            s = hp[0] + hp[240];  // exact int counts
        } else {
            s = hist_g[bd * 240 + tid];
        }
        xrow[q][k] = g_in[k] * (s * BN_INV) + b_in[k];
    }
    __syncthreads();

    // layer 1: 30 -> 128 (lane j computes outputs j and j+64); wave wid = q
    {
        float a0 = 0.f, a1 = 0.f;
#pragma unroll
        for (int k = 0; k < 30; ++k) {
            float xk = xrow[wid][k];
            a0 += xk * W0[k * 128 + lane];
            a1 += xk * W0[k * 128 + 64 + lane];
        }
        a0 += b0[lane]; a1 += b0[lane + 64];
        h1s[wid][lane]      = tanh_fast(g0[lane]      * (a0 * BN_INV) + be0[lane]);
        h1s[wid][lane + 64] = tanh_fast(g0[lane + 64] * (a1 * BN_INV) + be0[lane + 64]);
    }
    __syncthreads();

    // layer 2: 128 -> 64
    {
        float a = 0.f;
#pragma unroll 8
        for (int k = 0; k < 128; ++k) a += h1s[wid][k] * W1[k * 64 + lane];
        a += b1[lane];
        h2s[wid][lane] = tanh_fast(g1[lane] * (a * BN_INV) + be1[lane]);
    }
    __syncthreads();

    // layer 3: 64 -> 32 (written and read within wave wid — no barrier needed
    // before layer 4; compiler's lgkmcnt ordering covers same-wave LDS).
    if (lane < 32) {
        float a = 0.f;
#pragma unroll 8
        for (int k = 0; k < 64; ++k) a += h2s[wid][k] * W2[k * 32 + lane];
        a += b2[lane];
        h3s[wid][lane] = tanh_fast(g2[lane] * (a * BN_INV) + be2[lane]);
    }

    // layer 4: 32 -> 1, gate weighting (same wave as layer-3 writers)
    if (lane == 0) {
        float a = 0.f;
#pragma unroll
        for (int k = 0; k < 32; ++k) a += h3s[wid][k] * W3[k];
        a += b3[0];
        float y = tanh_fast(g3[0] * (a * BN_INV) + be3[0]);
        part[wid] = gate_s[wid] * y;
    }
    __syncthreads();

    if (tid == 0) {
        float s = 0.f;
#pragma unroll
        for (int q = 0; q < 8; ++q) s += part[q];
        out[bd] = s;
    }
}

extern "C" void kernel_launch(void* const* d_in, const int* in_sizes, int n_in,
                              void* d_out, int out_size, void* d_ws, size_t ws_size,
                              hipStream_t stream) {
    (void)in_sizes; (void)n_in; (void)out_size;
    const int*   doc    = (const int*)d_in[0];
    const int*   query  = (const int*)d_in[1];
    const float* emb    = (const float*)d_in[2];
    const float* idf    = (const float*)d_in[3];
    const float* w_gate = (const float*)d_in[4];
    const float* g_in   = (const float*)d_in[5];
    const float* b_in   = (const float*)d_in[6];
    const float* W0  = (const float*)d_in[7];
    const float* b0  = (const float*)d_in[8];
    const float* g0  = (const float*)d_in[9];
    const float* be0 = (const float*)d_in[10];
    const float* W1  = (const float*)d_in[11];
    const float* b1  = (const float*)d_in[12];
    const float* g1  = (const float*)d_in[13];
    const float* be1 = (const float*)d_in[14];
    const float* W2  = (const float*)d_in[15];
    const float* b2  = (const float*)d_in[16];
    const float* g2  = (const float*)d_in[17];
    const float* be2 = (const float*)d_in[18];
    const float* W3  = (const float*)d_in[19];
    const float* b3  = (const float*)d_in[20];
    const float* g3  = (const float*)d_in[21];
    const float* be3 = (const float*)d_in[22];

    float* hist_g = (float*)d_ws;
    const size_t need_partial = (size_t)1024 * 240 * sizeof(float); // 983 KB

    if (ws_size >= need_partial) {
        drmm_hist<true><<<dim3(1024), dim3(256), 0, stream>>>(doc, query, emb, hist_g);
        drmm_mlp<true><<<dim3(512), dim3(512), 0, stream>>>(
            hist_g, query, idf, w_gate, g_in, b_in,
            W0, b0, g0, be0, W1, b1, g1, be1,
            W2, b2, g2, be2, W3, b3, g3, be3, (float*)d_out);
    } else {
        hipMemsetAsync(hist_g, 0, 512 * 240 * sizeof(float), stream);
        drmm_hist<false><<<dim3(1024), dim3(256), 0, stream>>>(doc, query, emb, hist_g);
        drmm_mlp<false><<<dim3(512), dim3(512), 0, stream>>>(
            hist_g, query, idf, w_gate, g_in, b_in,
            W0, b0, g0, be0, W1, b1, g1, be1,
            W2, b2, g2, be2, W3, b3, g3, be3, (float*)d_out);
    }
}